// Round 7
// baseline (2476.066 us; speedup 1.0000x reference)
//
#include <hip/hip_runtime.h>
#include <hip/hip_bf16.h>

// VanillaRNN on MI355X — persistent cooperative kernel, XCD-local h exchange, v3.
// h_t = tanh(x_t @ W_hx^T + h_{t-1} @ W_hh^T + b_hx + b_hh)  (hh term skipped at t=0)
// out = h_last @ W_out^T + b_out
//
// grp = XCC_ID (32 batch rows), slot = per-XCD atomic (64 hidden cols).
// 8-way K-split across waves (wave kh owns all 64 cols x K-slice 256): h slice
// read EXACTLY ONCE per block per step (128 KB), no cg duplication.
// whh[4][8] = 128 regs/lane persistent. h loads: 16 asm sc0 dwordx4 issued
// up-front, counted vmcnt(12/8/4/0) + sched_barrier (never drain mid-stream).
// 2-stage LDS reduce (8 K-partials), epilogue split across 4 waves.

#define BB 256
#define SS 128
#define II 512
#define HH 2048
#define OO 10

#define NTHR 512
#define NBLK 256
#define LDS_BYTES 65536   // 32 KB stage-A + 32 KB stage-B, [j][lane] f32x4 (conflict-free)

typedef __attribute__((ext_vector_type(8))) __bf16 bf16x8;
typedef __attribute__((ext_vector_type(4))) __bf16 bf16x4;
typedef __attribute__((ext_vector_type(4))) float f32x4;
typedef unsigned long long u64;

__device__ __forceinline__ bf16x8 cvt8(float4 f0, float4 f1) {
    bf16x8 r;
    r[0] = (__bf16)f0.x; r[1] = (__bf16)f0.y; r[2] = (__bf16)f0.z; r[3] = (__bf16)f0.w;
    r[4] = (__bf16)f1.x; r[5] = (__bf16)f1.y; r[6] = (__bf16)f1.z; r[7] = (__bf16)f1.w;
    return r;
}

__global__ __launch_bounds__(256) void cvt_f32_bf16(const float* __restrict__ in,
                                                    __bf16* __restrict__ out, int n4) {
    int stride = gridDim.x * blockDim.x;
    for (int i = blockIdx.x * blockDim.x + threadIdx.x; i < n4; i += stride) {
        float4 v = reinterpret_cast<const float4*>(in)[i];
        bf16x4 o;
        o[0] = (__bf16)v.x; o[1] = (__bf16)v.y; o[2] = (__bf16)v.z; o[3] = (__bf16)v.w;
        *reinterpret_cast<bf16x4*>(out + 4 * (size_t)i) = o;
    }
}

#define AGLD(p) __hip_atomic_load((p), __ATOMIC_RELAXED, __HIP_MEMORY_SCOPE_AGENT)

// sc0 load: L1-bypass, agent-coherent; hits dirty same-XCD L2 lines; TA-coalesced.
#define LD1(dst, base, off)                                                     \
    asm volatile("global_load_dwordx4 %0, %1, off offset:" #off " sc0"          \
                 : "=&v"(dst) : "v"(base));

#define WAITN(n)                                                                \
    asm volatile("s_waitcnt vmcnt(" #n ")" ::: "memory");                       \
    __builtin_amdgcn_sched_barrier(0);

// Group g consumes hv[4g..4g+3] = kc {2g,2g+1} x rf {0,1}: 16 MFMAs.
#define MFMAG(G)                                                                \
    _Pragma("unroll")                                                           \
    for (int kc = 2*(G); kc < 2*(G) + 2; ++kc)                                  \
        _Pragma("unroll")                                                       \
        for (int cf = 0; cf < 4; ++cf)                                          \
            _Pragma("unroll")                                                   \
            for (int rf = 0; rf < 2; ++rf)                                      \
                acc[cf][rf] = __builtin_amdgcn_mfma_f32_16x16x32_bf16(          \
                    whh[cf][kc], hv[kc * 2 + rf], acc[cf][rf], 0, 0, 0);

extern "C" __global__ void __launch_bounds__(NTHR, 2) rnn_persist(
    const float*  __restrict__ x,      // [B][S][I] fp32
    const __bf16* __restrict__ Whh,    // [H][H] bf16 prepacked
    const __bf16* __restrict__ Whx,    // [H][I] bf16 prepacked
    const float*  __restrict__ bhx,    // [H]
    const float*  __restrict__ bhh,    // [H]
    __bf16* __restrict__ hb0,          // [B][H] ping
    __bf16* __restrict__ hb1,          // [B][H] pong
    unsigned* __restrict__ ctrs)       // [1024] zeroed: slot[g]=g*64, bar[g]=512+g*64
{
    extern __shared__ __align__(16) char lds[];
    const int tid = threadIdx.x;

    unsigned xcc;
    asm volatile("s_getreg_b32 %0, hwreg(HW_REG_XCC_ID)" : "=s"(xcc));
    const int grp = (int)(xcc & 7u);

    __shared__ unsigned slot_sh;
    if (tid == 0)
        slot_sh = __hip_atomic_fetch_add(ctrs + grp * 64, 1u, __ATOMIC_RELAXED,
                                         __HIP_MEMORY_SCOPE_AGENT);
    __syncthreads();
    const int slot = (int)(slot_sh & 31u);

    const int lane = tid & 63;
    const int kh   = tid >> 6;          // wave id 0..7 = K-split slice
    const int lq   = lane >> 4;         // 0..3
    const int lr   = lane & 15;
    const int colbase = slot * 64;      // hidden cols [colbase, +64)
    const int rowbase = grp * 32;       // batch rows  [rowbase, +32)

    // ---- W_hh fragments -> registers (persistent, 128 VGPR/lane) ----
    // wave kh: cols colbase+cf*16+lr, K slice [kh*256, +256), k = kc*32 + lq*8.
    bf16x8 whh[4][8];
#pragma unroll
    for (int cf = 0; cf < 4; ++cf) {
        const __bf16* wp = Whh + (size_t)(colbase + cf * 16 + lr) * HH + kh * 256 + lq * 8;
#pragma unroll
        for (int kc = 0; kc < 8; ++kc)
            whh[cf][kc] = *reinterpret_cast<const bf16x8*>(wp + kc * 32);
    }

    // ---- biases for epilogue (waves 0..3 use cf == kh slice) ----
    const int ecol0 = colbase + (kh & 3) * 16 + 4 * lq;   // 4 consecutive cols
    const float4 bx4 = *reinterpret_cast<const float4*>(bhx + ecol0);
    const float4 bh4 = *reinterpret_cast<const float4*>(bhh + ecol0);

    unsigned* bar = ctrs + 512 + grp * 64;

    for (int s = 0; s < SS - 1; ++s) {
        const __bf16* hr = (s & 1) ? hb0 : hb1;
        __bf16*       hw = (s & 1) ? hb1 : hb0;

        f32x4 acc[4][2] = {};   // [cf][rf]

        // ---- x-projection, K=512 split 8 ways (64/wave); overlaps barrier wait ----
        {
            bf16x8 wxf[4][2], xf[2][2];
#pragma unroll
            for (int cf = 0; cf < 4; ++cf) {
                const __bf16* wp = Whx + (size_t)(colbase + cf * 16 + lr) * II + kh * 64 + lq * 8;
#pragma unroll
                for (int kc = 0; kc < 2; ++kc)
                    wxf[cf][kc] = *reinterpret_cast<const bf16x8*>(wp + kc * 32);
            }
#pragma unroll
            for (int rf = 0; rf < 2; ++rf) {
                const float* xp = x + (size_t)(rowbase + rf * 16 + lr) * (SS * II)
                                  + (size_t)s * II + kh * 64 + lq * 8;
#pragma unroll
                for (int kc = 0; kc < 2; ++kc) {
                    float4 f0 = *reinterpret_cast<const float4*>(xp + kc * 32);
                    float4 f1 = *reinterpret_cast<const float4*>(xp + kc * 32 + 4);
                    xf[rf][kc] = cvt8(f0, f1);
                }
            }
#pragma unroll
            for (int kc = 0; kc < 2; ++kc)
#pragma unroll
                for (int cf = 0; cf < 4; ++cf)
#pragma unroll
                    for (int rf = 0; rf < 2; ++rf)
                        acc[cf][rf] = __builtin_amdgcn_mfma_f32_16x16x32_bf16(
                            wxf[cf][kc], xf[rf][kc], acc[cf][rf], 0, 0, 0);
        }

        if (s > 0) {
            // ---- per-XCD barrier wait (arrivals of step s-1) ----
            if (tid == 0) {
                const unsigned target = (unsigned)s * 32u;
                unsigned polls = 0;
                while (AGLD(bar) < target) {
                    __builtin_amdgcn_s_sleep(1);
                    if (++polls > (1u << 20)) break;   // no-hang safety valve
                }
            }
            __syncthreads();

            // ---- hh part: issue ALL 16 h loads, counted waits, 64 MFMAs ----
            const char* p0 = (const char*)(hr + (size_t)(rowbase + lr) * HH + kh * 256 + lq * 8);
            const char* p1 = (const char*)(hr + (size_t)(rowbase + 16 + lr) * HH + kh * 256 + lq * 8);
            bf16x8 hv[16];
            WAITN(0)                        // exact vmcnt baseline
            LD1(hv[0],  p0, 0)   LD1(hv[1],  p1, 0)
            LD1(hv[2],  p0, 64)  LD1(hv[3],  p1, 64)
            LD1(hv[4],  p0, 128) LD1(hv[5],  p1, 128)
            LD1(hv[6],  p0, 192) LD1(hv[7],  p1, 192)
            LD1(hv[8],  p0, 256) LD1(hv[9],  p1, 256)
            LD1(hv[10], p0, 320) LD1(hv[11], p1, 320)
            LD1(hv[12], p0, 384) LD1(hv[13], p1, 384)
            LD1(hv[14], p0, 448) LD1(hv[15], p1, 448)
            WAITN(12) MFMAG(0)
            WAITN(8)  MFMAG(1)
            WAITN(4)  MFMAG(2)
            WAITN(0)  MFMAG(3)
        }

        // ---- stage A: waves 4..7 -> LDS [region][j][lane] f32x4 (conflict-free) ----
        if (kh >= 4) {
            char* base = lds + (size_t)(kh - 4) * 8192 + (size_t)lane * 16;
#pragma unroll
            for (int cf = 0; cf < 4; ++cf)
#pragma unroll
                for (int rf = 0; rf < 2; ++rf)
                    *reinterpret_cast<f32x4*>(base + (cf * 2 + rf) * 1024) = acc[cf][rf];
        }
        __syncthreads();
        if (kh < 4) {
            char* base = lds + (size_t)kh * 8192 + (size_t)lane * 16;
#pragma unroll
            for (int cf = 0; cf < 4; ++cf)
#pragma unroll
                for (int rf = 0; rf < 2; ++rf)
                    acc[cf][rf] += *reinterpret_cast<const f32x4*>(base + (cf * 2 + rf) * 1024);
            // ---- stage B write: give away cf != kh slices ----
            char* bb = lds + 32768 + (size_t)kh * 8192 + (size_t)lane * 16;
#pragma unroll
            for (int cf = 0; cf < 4; ++cf)
                if (cf != kh)
#pragma unroll
                    for (int rf = 0; rf < 2; ++rf)
                        *reinterpret_cast<f32x4*>(bb + (cf * 2 + rf) * 1024) = acc[cf][rf];
        }
        __syncthreads();
        if (kh < 4) {
            // ---- collect partners' cf == kh slices, epilogue for 16 cols ----
#pragma unroll
            for (int p = 0; p < 4; ++p)
                if (p != kh) {
                    const char* pb = lds + 32768 + (size_t)p * 8192 + (size_t)lane * 16;
#pragma unroll
                    for (int rf = 0; rf < 2; ++rf)
                        acc[kh][rf] += *reinterpret_cast<const f32x4*>(pb + (kh * 2 + rf) * 1024);
                }
#pragma unroll
            for (int rf = 0; rf < 2; ++rf) {
                union { unsigned short u[4]; u64 ll; } P;
#pragma unroll
                for (int e = 0; e < 4; ++e) {
                    const float bias = ((const float*)&bx4)[e] +
                                       (s > 0 ? ((const float*)&bh4)[e] : 0.0f);
                    __bf16 v = (__bf16)tanhf(acc[kh][rf][e] + bias);
                    P.u[e] = __builtin_bit_cast(unsigned short, v);
                }
                *reinterpret_cast<u64*>(
                    hw + (size_t)(rowbase + rf * 16 + lr) * HH + ecol0) = P.ll;
            }
            asm volatile("s_waitcnt vmcnt(0)" ::: "memory");   // stores in L2
        }
        __syncthreads();   // SB2: all stores of this step complete
        if (s < SS - 2 && tid == 0)
            __hip_atomic_fetch_add(bar, 1u, __ATOMIC_RELAXED, __HIP_MEMORY_SCOPE_AGENT);
    }
}

// out[b][o] = sum_h h[b][h] * W_out[o][h] + b_out[o]; one block per batch row.
__global__ __launch_bounds__(256) void rnn_out(
    const __bf16* __restrict__ h, const float* __restrict__ W_out,
    const float* __restrict__ b_out, float* __restrict__ out)
{
    const int b = blockIdx.x;
    const int tid = threadIdx.x;
    __shared__ float red[OO][4];

    float hv[8];
#pragma unroll
    for (int e = 0; e < 8; ++e)
        hv[e] = (float)h[(size_t)b * HH + tid + e * 256];

#pragma unroll
    for (int o = 0; o < OO; ++o) {
        float s = 0.0f;
#pragma unroll
        for (int e = 0; e < 8; ++e)
            s += hv[e] * W_out[(size_t)o * HH + tid + e * 256];
        for (int off = 32; off; off >>= 1) s += __shfl_down(s, off);
        if ((tid & 63) == 0) red[o][tid >> 6] = s;
    }
    __syncthreads();
    if (tid < OO) {
        float s = red[tid][0] + red[tid][1] + red[tid][2] + red[tid][3];
        out[(size_t)b * OO + tid] = s + b_out[tid];
    }
}

extern "C" void kernel_launch(void* const* d_in, const int* in_sizes, int n_in,
                              void* d_out, int out_size, void* d_ws, size_t ws_size,
                              hipStream_t stream) {
    (void)in_sizes; (void)n_in; (void)out_size; (void)ws_size;

    const float* x     = (const float*)d_in[0];
    const float* W_hx  = (const float*)d_in[1];
    const float* b_hx  = (const float*)d_in[2];
    const float* W_hh  = (const float*)d_in[3];
    const float* b_hh  = (const float*)d_in[4];
    const float* W_out = (const float*)d_in[5];
    const float* b_out = (const float*)d_in[6];
    float* out = (float*)d_out;

    char* ws = (char*)d_ws;
    __bf16*   hb0    = (__bf16*)ws;                                   // 1 MB
    __bf16*   hb1    = hb0 + (size_t)BB * HH;                         // 1 MB
    unsigned* ctrs   = (unsigned*)(ws + 2 * (size_t)BB * HH * 2);     // 4 KB
    __bf16*   Whh_bf = (__bf16*)(ws + 2 * (size_t)BB * HH * 2 + 4096);// 8 MB
    __bf16*   Whx_bf = Whh_bf + (size_t)HH * HH;                      // 2 MB

    hipMemsetAsync(ctrs, 0, 4096, stream);
    cvt_f32_bf16<<<1024, 256, 0, stream>>>(W_hh, Whh_bf, HH * HH / 4);
    cvt_f32_bf16<<<512, 256, 0, stream>>>(W_hx, Whx_bf, HH * II / 4);

    static bool attr_set = false;   // host-side one-time setup (same effect every call)
    if (!attr_set) {
        hipFuncSetAttribute(reinterpret_cast<const void*>(rnn_persist),
                            hipFuncAttributeMaxDynamicSharedMemorySize, LDS_BYTES);
        attr_set = true;
    }

    void* args[] = {(void*)&x, (void*)&Whh_bf, (void*)&Whx_bf, (void*)&b_hx,
                    (void*)&b_hh, (void*)&hb0, (void*)&hb1, (void*)&ctrs};
    hipError_t e = hipLaunchCooperativeKernel(
        reinterpret_cast<const void*>(rnn_persist),
        dim3(NBLK), dim3(NTHR), args, LDS_BYTES, stream);
    if (e != hipSuccess) {
        // Fallback: plain launch. High reg use -> 1 block/CU, grid == CU count,
        // so all blocks co-resident; barrier spin has a timeout regardless.
        rnn_persist<<<dim3(NBLK), dim3(NTHR), LDS_BYTES, stream>>>(
            x, Whh_bf, Whx_bf, b_hx, b_hh, hb0, hb1, ctrs);
    }

    // 127 steps: step s writes (s&1)?hb1:hb0; s=126 (even) -> hb0 holds h_last.
    rnn_out<<<BB, 256, 0, stream>>>(hb0, W_out, b_out, out);
}

// Round 8
// 1767.865 us; speedup vs baseline: 1.4006x; 1.4006x over previous
//
#include <hip/hip_runtime.h>
#include <hip/hip_bf16.h>

// VanillaRNN on MI355X — persistent cooperative kernel, XCD-local h exchange, v4.
// h_t = tanh(x_t @ W_hx^T + h_{t-1} @ W_hh^T + b_hx + b_hh)  (hh term skipped at t=0)
// out = h_last @ W_out^T + b_out
//
// grp = XCC_ID (32 batch rows), slot = per-XCD atomic (64 hidden cols).
// Wave kh (0..7) owns K-slice [kh*256,+256) of the block's [32 rows x 64 cols] tile.
// W_hh: kc 0-2 of each wave's slice in LDS (96 KB, XOR-swizzled, loaded once);
// kc 3-7 streamed per step via plain cached loads (same addresses every step ->
// L2-resident 5 MB/XCD). h frags: 16 asm sc0 dwordx4, counted vmcnt(12/8/4/0).
// x pre-converted to bf16. 4-sync LDS reduce (32 KB region reused A/B stage).

#define BB 256
#define SS 128
#define II 512
#define HH 2048
#define OO 10

#define NTHR 512
#define NBLK 256
#define LDS_W   98304                    // 8 waves * 12288 B ([64 cols x 96 K] bf16)
#define LDS_RED 32768                    // 4 regions * 8 KB (reused stage A/B)
#define LDS_BYTES (LDS_W + LDS_RED)      // 131072

typedef __attribute__((ext_vector_type(8))) __bf16 bf16x8;
typedef __attribute__((ext_vector_type(4))) __bf16 bf16x4;
typedef __attribute__((ext_vector_type(4))) float f32x4;
typedef unsigned long long u64;

__device__ __forceinline__ f32x4 mfma_(bf16x8 a, bf16x8 b, f32x4 c) {
    return __builtin_amdgcn_mfma_f32_16x16x32_bf16(a, b, c, 0, 0, 0);
}

__global__ __launch_bounds__(256) void cvt_f32_bf16(const float* __restrict__ in,
                                                    __bf16* __restrict__ out, int n4) {
    int stride = gridDim.x * blockDim.x;
    for (int i = blockIdx.x * blockDim.x + threadIdx.x; i < n4; i += stride) {
        float4 v = reinterpret_cast<const float4*>(in)[i];
        bf16x4 o;
        o[0] = (__bf16)v.x; o[1] = (__bf16)v.y; o[2] = (__bf16)v.z; o[3] = (__bf16)v.w;
        *reinterpret_cast<bf16x4*>(out + 4 * (size_t)i) = o;
    }
}

#define AGLD(p) __hip_atomic_load((p), __ATOMIC_RELAXED, __HIP_MEMORY_SCOPE_AGENT)

// sc0 load: L1-bypass, agent-coherent; hits dirty same-XCD L2 lines; TA-coalesced.
#define LD1(dst, base, off)                                                     \
    asm volatile("global_load_dwordx4 %0, %1, off offset:" #off " sc0"          \
                 : "=&v"(dst) : "v"(base));

#define WAITN(n)                                                                \
    asm volatile("s_waitcnt vmcnt(" #n ")" ::: "memory");                       \
    __builtin_amdgcn_sched_barrier(0);

extern "C" __global__ void __launch_bounds__(NTHR)
__attribute__((amdgpu_waves_per_eu(1, 2))) rnn_persist(
    const __bf16* __restrict__ xbf,    // [B][S][I] bf16 prepacked
    const __bf16* __restrict__ Whh,    // [H][H] bf16 prepacked
    const __bf16* __restrict__ Whx,    // [H][I] bf16 prepacked
    const float*  __restrict__ bhx,    // [H]
    const float*  __restrict__ bhh,    // [H]
    __bf16* __restrict__ hb0,          // [B][H] ping
    __bf16* __restrict__ hb1,          // [B][H] pong
    unsigned* __restrict__ ctrs)       // [1024] zeroed: slot[g]=g*64, bar[g]=512+g*64
{
    extern __shared__ __align__(16) char lds[];
    const int tid = threadIdx.x;

    unsigned xcc;
    asm volatile("s_getreg_b32 %0, hwreg(HW_REG_XCC_ID)" : "=s"(xcc));
    const int grp = (int)(xcc & 7u);

    __shared__ unsigned slot_sh;
    if (tid == 0)
        slot_sh = __hip_atomic_fetch_add(ctrs + grp * 64, 1u, __ATOMIC_RELAXED,
                                         __HIP_MEMORY_SCOPE_AGENT);
    __syncthreads();
    const int slot = (int)(slot_sh & 31u);

    const int lane = tid & 63;
    const int kh   = tid >> 6;          // wave id 0..7 = K-slice [kh*256,+256)
    const int lq   = lane >> 4;         // 0..3
    const int lr   = lane & 15;
    const int colbase = slot * 64;      // hidden cols [colbase, +64)
    const int rowbase = grp * 32;       // batch rows  [rowbase, +32)

    // ---- stage W_hh kc 0-2 -> LDS (swizzled), once; wave kh stages its region ----
    {
        const unsigned wb = (unsigned)kh * 12288u;
#pragma unroll
        for (int it = 0; it < 12; ++it) {
            const int f   = lane + it * 64;    // 0..767
            const int col = f / 12;
            const int kq  = f % 12;            // 16B unit within 96-K row
            bf16x8 v = *reinterpret_cast<const bf16x8*>(
                Whh + (size_t)(colbase + col) * HH + kh * 256 + kq * 8);
            *reinterpret_cast<bf16x8*>(
                lds + ((wb + (unsigned)col * 192u + (unsigned)kq * 16u)
                       ^ ((unsigned)(col & 7) << 4))) = v;
        }
    }

    // LDS A-frag read (kc 0..2): col = cf*16+lr, k2 = kc*32+lq*8.
    const unsigned wswz = (unsigned)(lr & 7) << 4;
    const unsigned abase = (unsigned)kh * 12288u + (unsigned)lr * 192u + (unsigned)lq * 16u;
#define LDSA(cf, kc)                                                            \
    (*reinterpret_cast<const bf16x8*>(                                          \
        lds + ((abase + (unsigned)(cf) * 3072u + (unsigned)(kc) * 64u) ^ wswz)))

    // ---- biases for epilogue (waves 0..3, slice cf == kh) ----
    const int ecol0 = colbase + (kh & 3) * 16 + 4 * lq;
    const float4 bx4 = *reinterpret_cast<const float4*>(bhx + ecol0);
    const float4 bh4 = *reinterpret_cast<const float4*>(bhh + ecol0);

    unsigned* bar = ctrs + 512 + grp * 64;
    float* red = reinterpret_cast<float*>(lds + LDS_W);

    __syncthreads();   // W staging complete

    for (int s = 0; s < SS - 1; ++s) {
        const __bf16* hr = (s & 1) ? hb0 : hb1;
        __bf16*       hw = (s & 1) ? hb1 : hb0;

        f32x4 acc[4][2] = {};   // [cf][rf]

        // ---- streamed W (kc 3..7): plain cached loads, same addr every step ----
        bf16x8 wv[20];
        {
            const __bf16* wp = Whh + (size_t)(colbase + lr) * HH + kh * 256 + lq * 8;
#pragma unroll
            for (int kc = 3; kc < 8; ++kc)
#pragma unroll
                for (int cf = 0; cf < 4; ++cf)
                    wv[(kc - 3) * 4 + cf] = *reinterpret_cast<const bf16x8*>(
                        wp + (size_t)cf * 16 * HH + kc * 32);
        }

        // ---- x-projection, K=512 split 8 ways (64/wave); overlaps barrier wait ----
        {
            bf16x8 wxf[4][2], xf[2][2];
#pragma unroll
            for (int cf = 0; cf < 4; ++cf) {
                const __bf16* wp = Whx + (size_t)(colbase + cf * 16 + lr) * II + kh * 64 + lq * 8;
#pragma unroll
                for (int kc = 0; kc < 2; ++kc)
                    wxf[cf][kc] = *reinterpret_cast<const bf16x8*>(wp + kc * 32);
            }
#pragma unroll
            for (int rf = 0; rf < 2; ++rf) {
                const __bf16* xp = xbf + (size_t)(rowbase + rf * 16 + lr) * (SS * II)
                                   + (size_t)s * II + kh * 64 + lq * 8;
#pragma unroll
                for (int kc = 0; kc < 2; ++kc)
                    xf[rf][kc] = *reinterpret_cast<const bf16x8*>(xp + kc * 32);
            }
#pragma unroll
            for (int kc = 0; kc < 2; ++kc)
#pragma unroll
                for (int cf = 0; cf < 4; ++cf)
#pragma unroll
                    for (int rf = 0; rf < 2; ++rf)
                        acc[cf][rf] = mfma_(wxf[cf][kc], xf[rf][kc], acc[cf][rf]);
        }

        if (s > 0) {
            // ---- per-XCD barrier wait (arrivals of step s-1) ----
            if (tid == 0) {
                const unsigned target = (unsigned)s * 32u;
                unsigned polls = 0;
                while (AGLD(bar) < target) {
                    __builtin_amdgcn_s_sleep(1);
                    if (++polls > (1u << 20)) break;   // no-hang safety valve
                }
            }
            __syncthreads();

            // ---- hh: 16 h loads (sc0 asm, counted), A from LDS (kc0-2) / wv (kc3-7) ----
            const char* p0 = (const char*)(hr + (size_t)(rowbase + lr) * HH + kh * 256 + lq * 8);
            const char* p1 = (const char*)(hr + (size_t)(rowbase + 16 + lr) * HH + kh * 256 + lq * 8);
            bf16x8 hv[16];
            WAITN(0)                        // drain plain loads -> exact vmcnt baseline
            LD1(hv[0],  p0, 0)   LD1(hv[1],  p1, 0)
            LD1(hv[2],  p0, 64)  LD1(hv[3],  p1, 64)
            LD1(hv[4],  p0, 128) LD1(hv[5],  p1, 128)
            LD1(hv[6],  p0, 192) LD1(hv[7],  p1, 192)
            LD1(hv[8],  p0, 256) LD1(hv[9],  p1, 256)
            LD1(hv[10], p0, 320) LD1(hv[11], p1, 320)
            LD1(hv[12], p0, 384) LD1(hv[13], p1, 384)
            LD1(hv[14], p0, 448) LD1(hv[15], p1, 448)
            WAITN(12)   // kc 0,1 ready (LDS A)
#pragma unroll
            for (int kc = 0; kc < 2; ++kc)
#pragma unroll
                for (int cf = 0; cf < 4; ++cf) {
                    bf16x8 a_ = LDSA(cf, kc);
                    acc[cf][0] = mfma_(a_, hv[kc * 2 + 0], acc[cf][0]);
                    acc[cf][1] = mfma_(a_, hv[kc * 2 + 1], acc[cf][1]);
                }
            WAITN(8)    // kc 2 (LDS), kc 3 (wv)
#pragma unroll
            for (int cf = 0; cf < 4; ++cf) {
                bf16x8 a_ = LDSA(cf, 2);
                acc[cf][0] = mfma_(a_, hv[4], acc[cf][0]);
                acc[cf][1] = mfma_(a_, hv[5], acc[cf][1]);
            }
#pragma unroll
            for (int cf = 0; cf < 4; ++cf) {
                acc[cf][0] = mfma_(wv[cf], hv[6], acc[cf][0]);
                acc[cf][1] = mfma_(wv[cf], hv[7], acc[cf][1]);
            }
            WAITN(4)    // kc 4,5
#pragma unroll
            for (int kc = 4; kc < 6; ++kc)
#pragma unroll
                for (int cf = 0; cf < 4; ++cf) {
                    bf16x8 a_ = wv[(kc - 3) * 4 + cf];
                    acc[cf][0] = mfma_(a_, hv[kc * 2 + 0], acc[cf][0]);
                    acc[cf][1] = mfma_(a_, hv[kc * 2 + 1], acc[cf][1]);
                }
            WAITN(0)    // kc 6,7
#pragma unroll
            for (int kc = 6; kc < 8; ++kc)
#pragma unroll
                for (int cf = 0; cf < 4; ++cf) {
                    bf16x8 a_ = wv[(kc - 3) * 4 + cf];
                    acc[cf][0] = mfma_(a_, hv[kc * 2 + 0], acc[cf][0]);
                    acc[cf][1] = mfma_(a_, hv[kc * 2 + 1], acc[cf][1]);
                }
        }

        // ---- stage A: waves 4..7 -> red regions 0..3 ([j][lane] f32x4) ----
        if (kh >= 4) {
            char* base = (char*)red + (size_t)(kh - 4) * 8192 + (size_t)lane * 16;
#pragma unroll
            for (int cf = 0; cf < 4; ++cf)
#pragma unroll
                for (int rf = 0; rf < 2; ++rf)
                    *reinterpret_cast<f32x4*>(base + (cf * 2 + rf) * 1024) = acc[cf][rf];
        }
        __syncthreads();
        if (kh < 4) {
            char* base = (char*)red + (size_t)kh * 8192 + (size_t)lane * 16;
#pragma unroll
            for (int cf = 0; cf < 4; ++cf)
#pragma unroll
                for (int rf = 0; rf < 2; ++rf)
                    acc[cf][rf] += *reinterpret_cast<const f32x4*>(base + (cf * 2 + rf) * 1024);
            // ---- stage B (reuse same region): give away cf != kh slices ----
#pragma unroll
            for (int cf = 0; cf < 4; ++cf)
                if (cf != kh)
#pragma unroll
                    for (int rf = 0; rf < 2; ++rf)
                        *reinterpret_cast<f32x4*>(base + (cf * 2 + rf) * 1024) = acc[cf][rf];
        }
        __syncthreads();
        if (kh < 4) {
            // ---- collect partners' cf == kh slices, epilogue for 16 cols ----
#pragma unroll
            for (int p = 0; p < 4; ++p)
                if (p != kh) {
                    const char* pb = (const char*)red + (size_t)p * 8192 + (size_t)lane * 16;
#pragma unroll
                    for (int rf = 0; rf < 2; ++rf)
                        acc[kh][rf] += *reinterpret_cast<const f32x4*>(pb + (kh * 2 + rf) * 1024);
                }
#pragma unroll
            for (int rf = 0; rf < 2; ++rf) {
                union { unsigned short u[4]; u64 ll; } P;
#pragma unroll
                for (int e = 0; e < 4; ++e) {
                    const float bias = ((const float*)&bx4)[e] +
                                       (s > 0 ? ((const float*)&bh4)[e] : 0.0f);
                    __bf16 v = (__bf16)tanhf(acc[kh][rf][e] + bias);
                    P.u[e] = __builtin_bit_cast(unsigned short, v);
                }
                *reinterpret_cast<u64*>(
                    hw + (size_t)(rowbase + rf * 16 + lr) * HH + ecol0) = P.ll;
            }
            asm volatile("s_waitcnt vmcnt(0)" ::: "memory");   // stores in L2
        }
        __syncthreads();   // SB2: all stores of this step complete
        if (s < SS - 2 && tid == 0)
            __hip_atomic_fetch_add(bar, 1u, __ATOMIC_RELAXED, __HIP_MEMORY_SCOPE_AGENT);
    }
#undef LDSA
}

// out[b][o] = sum_h h[b][h] * W_out[o][h] + b_out[o]; one block per batch row.
__global__ __launch_bounds__(256) void rnn_out(
    const __bf16* __restrict__ h, const float* __restrict__ W_out,
    const float* __restrict__ b_out, float* __restrict__ out)
{
    const int b = blockIdx.x;
    const int tid = threadIdx.x;
    __shared__ float red[OO][4];

    float hv[8];
#pragma unroll
    for (int e = 0; e < 8; ++e)
        hv[e] = (float)h[(size_t)b * HH + tid + e * 256];

#pragma unroll
    for (int o = 0; o < OO; ++o) {
        float s = 0.0f;
#pragma unroll
        for (int e = 0; e < 8; ++e)
            s += hv[e] * W_out[(size_t)o * HH + tid + e * 256];
        for (int off = 32; off; off >>= 1) s += __shfl_down(s, off);
        if ((tid & 63) == 0) red[o][tid >> 6] = s;
    }
    __syncthreads();
    if (tid < OO) {
        float s = red[tid][0] + red[tid][1] + red[tid][2] + red[tid][3];
        out[(size_t)b * OO + tid] = s + b_out[tid];
    }
}

extern "C" void kernel_launch(void* const* d_in, const int* in_sizes, int n_in,
                              void* d_out, int out_size, void* d_ws, size_t ws_size,
                              hipStream_t stream) {
    (void)in_sizes; (void)n_in; (void)out_size; (void)ws_size;

    const float* x     = (const float*)d_in[0];
    const float* W_hx  = (const float*)d_in[1];
    const float* b_hx  = (const float*)d_in[2];
    const float* W_hh  = (const float*)d_in[3];
    const float* b_hh  = (const float*)d_in[4];
    const float* W_out = (const float*)d_in[5];
    const float* b_out = (const float*)d_in[6];
    float* out = (float*)d_out;

    char* ws = (char*)d_ws;
    __bf16*   hb0    = (__bf16*)ws;                                   // 1 MB
    __bf16*   hb1    = hb0 + (size_t)BB * HH;                         // 1 MB
    unsigned* ctrs   = (unsigned*)(ws + 2 * (size_t)BB * HH * 2);     // 4 KB
    __bf16*   Whh_bf = (__bf16*)(ws + 2 * (size_t)BB * HH * 2 + 4096);// 8 MB
    __bf16*   Whx_bf = Whh_bf + (size_t)HH * HH;                      // 2 MB
    __bf16*   xbf    = Whx_bf + (size_t)HH * II;                      // 33.6 MB

    hipMemsetAsync(ctrs, 0, 4096, stream);
    cvt_f32_bf16<<<1024, 256, 0, stream>>>(W_hh, Whh_bf, HH * HH / 4);
    cvt_f32_bf16<<<512, 256, 0, stream>>>(W_hx, Whx_bf, HH * II / 4);
    cvt_f32_bf16<<<4096, 256, 0, stream>>>(x, xbf, BB * SS * II / 4);

    static bool attr_set = false;   // host-side one-time setup (same effect every call)
    if (!attr_set) {
        hipFuncSetAttribute(reinterpret_cast<const void*>(rnn_persist),
                            hipFuncAttributeMaxDynamicSharedMemorySize, LDS_BYTES);
        attr_set = true;
    }

    void* args[] = {(void*)&xbf, (void*)&Whh_bf, (void*)&Whx_bf, (void*)&b_hx,
                    (void*)&b_hh, (void*)&hb0, (void*)&hb1, (void*)&ctrs};
    hipError_t e = hipLaunchCooperativeKernel(
        reinterpret_cast<const void*>(rnn_persist),
        dim3(NBLK), dim3(NTHR), args, LDS_BYTES, stream);
    if (e != hipSuccess) {
        // Fallback: plain launch. 128 KiB LDS -> 1 block/CU, grid == CU count,
        // so all blocks co-resident; barrier spin has a timeout regardless.
        rnn_persist<<<dim3(NBLK), dim3(NTHR), LDS_BYTES, stream>>>(
            xbf, Whh_bf, Whx_bf, b_hx, b_hh, hb0, hb1, ctrs);
    }

    // 127 steps: step s writes (s&1)?hb1:hb0; s=126 (even) -> hb0 holds h_last.
    rnn_out<<<BB, 256, 0, stream>>>(hb0, W_out, b_out, out);
}